// Round 17
// baseline (67.491 us; speedup 1.0000x reference)
//
#include <hip/hip_runtime.h>

#define DD 256
#define HH 4

template <int CTRL>
__device__ __forceinline__ float dpp_add(float v) {
    const int t = __builtin_amdgcn_update_dpp(0, __float_as_int(v), CTRL, 0xF, 0xF, true);
    return v + __int_as_float(t);
}

// sum-to-all WITHIN each 32-lane half: 4 DPP levels + 1 shfl (xor16 stays in-half)
__device__ __forceinline__ float half_allsum(float v) {
    v = dpp_add<0xB1>(v);     // quad_perm [1,0,3,2]  (xor 1)
    v = dpp_add<0x4E>(v);     // quad_perm [2,3,0,1]  (xor 2)
    v = dpp_add<0x124>(v);    // row_ror:4
    v = dpp_add<0x128>(v);    // row_ror:8  -> row-of-16 sum
    v += __shfl_xor(v, 16);   // -> 32-lane-half sum
    return v;
}

// ONE WAVE per graph, SINGLE LAUNCH (r17): wave computes its own [s,e) via two
// wave-uniform binary searches on bi (L2/L3-resident) — removes the starts_kernel
// launch + inter-kernel gap. Engine identical to r16: single coalesced x pass,
// zero LDS/barriers, split-row pair reduction (half 0 reduces even row, half 1 odd;
// 3 DS + 4 DPP + 1 exp per 2 rows per head), no-max softmax (validated r7-r16).
__global__ __launch_bounds__(256) void fused_single(
    const float* __restrict__ x, const int* __restrict__ bi,
    const float* __restrict__ W, const float* __restrict__ b,
    const float* __restrict__ temp, float* __restrict__ ews,
    float* __restrict__ xp, float* __restrict__ aw, int N, int G) {

    const int lane = threadIdx.x & 63;
    const int half = lane >> 5;
    const int g = (int)((blockIdx.x * (size_t)blockDim.x + threadIdx.x) >> 6);
    if (g >= G) return;

    // wave-uniform binary searches: s = lower_bound(g), e = lower_bound(g+1)
    int lo = 0, hi = N;
    while (lo < hi) { const int mid = (lo + hi) >> 1; if (bi[mid] < g) lo = mid + 1; else hi = mid; }
    const int s = lo;
    int hi2 = N;                      // second search starts at lo = s
    while (lo < hi2) { const int mid = (lo + hi2) >> 1; if (bi[mid] < g + 1) lo = mid + 1; else hi2 = mid; }
    const int e = lo;
    const int cnt = e - s;

    if (cnt == 0) {
        ((float4*)xp)[(size_t)g * 64 + lane] = make_float4(0.f, 0.f, 0.f, 0.f);
        return;
    }

    const float4* __restrict__ x4 = (const float4*)x;
    const float4* __restrict__ W4 = (const float4*)W;
    const float4 w0 = W4[lane];            // lane's 4 columns of each head's W
    const float4 w1 = W4[64 + lane];
    const float4 w2 = W4[128 + lane];
    const float4 w3 = W4[192 + lane];
    const float invT = 1.0f / temp[0];
    const float b0 = b[0], b1 = b[1], b2 = b[2], b3 = b[3];

    const int ngrp = (cnt + 63) >> 6;      // almost always 1 (mean cnt ~31)

    float l0 = 0.f, l1 = 0.f, l2 = 0.f, l3 = 0.f;               // wave-uniform denom
    float4 ac0 = make_float4(0.f,0.f,0.f,0.f), ac1 = ac0, ac2 = ac0, ac3 = ac0;
    float4 em = make_float4(0.f, 0.f, 0.f, 0.f);                // my row's e (per group)

    for (int g0 = 0; g0 < cnt; g0 += 64) {
        const int gs = min(64, cnt - g0);
        for (int i = 0; i < gs; i += 4) {
            float4 xv[4];
            #pragma unroll
            for (int j = 0; j < 4; ++j) {
                const int r = s + g0 + i + j;
                xv[j] = x4[(size_t)(r < e ? r : e - 1) * 64 + lane];   // coalesced clause
            }
            #pragma unroll
            for (int pp = 0; pp < 2; ++pp) {
                const float4 xA = xv[2 * pp];
                const float4 xB = xv[2 * pp + 1];
                // per-lane 4-col partials for both rows, all heads
                const float pA0 = xA.x*w0.x + xA.y*w0.y + xA.z*w0.z + xA.w*w0.w;
                const float pA1 = xA.x*w1.x + xA.y*w1.y + xA.z*w1.z + xA.w*w1.w;
                const float pA2 = xA.x*w2.x + xA.y*w2.y + xA.z*w2.z + xA.w*w2.w;
                const float pA3 = xA.x*w3.x + xA.y*w3.y + xA.z*w3.z + xA.w*w3.w;
                const float pB0 = xB.x*w0.x + xB.y*w0.y + xB.z*w0.z + xB.w*w0.w;
                const float pB1 = xB.x*w1.x + xB.y*w1.y + xB.z*w1.z + xB.w*w1.w;
                const float pB2 = xB.x*w2.x + xB.y*w2.y + xB.z*w2.z + xB.w*w2.w;
                const float pB3 = xB.x*w3.x + xB.y*w3.y + xB.z*w3.z + xB.w*w3.w;
                // cross-half merge: half 0 keeps row A (sends B), half 1 keeps row B
                const float v0 = (half ? pB0 : pA0) + __shfl_xor(half ? pA0 : pB0, 32);
                const float v1 = (half ? pB1 : pA1) + __shfl_xor(half ? pA1 : pB1, 32);
                const float v2 = (half ? pB2 : pA2) + __shfl_xor(half ? pA2 : pB2, 32);
                const float v3 = (half ? pB3 : pA3) + __shfl_xor(half ? pA3 : pB3, 32);
                // reduce own row within the half; exp own row only
                const float eo0 = __expf((half_allsum(v0) + b0) * invT);
                const float eo1 = __expf((half_allsum(v1) + b1) * invT);
                const float eo2 = __expf((half_allsum(v2) + b2) * invT);
                const float eo3 = __expf((half_allsum(v3) + b3) * invT);
                // exchange finished e across halves
                const float eu0 = __shfl_xor(eo0, 32);
                const float eu1 = __shfl_xor(eo1, 32);
                const float eu2 = __shfl_xor(eo2, 32);
                const float eu3 = __shfl_xor(eo3, 32);
                const float eA0 = half ? eu0 : eo0, eB0 = half ? eo0 : eu0;
                const float eA1 = half ? eu1 : eo1, eB1 = half ? eo1 : eu1;
                const float eA2 = half ? eu2 : eo2, eB2 = half ? eo2 : eu2;
                const float eA3 = half ? eu3 : eo3, eB3 = half ? eo3 : eu3;

                const int iA = i + 2 * pp, iB = iA + 1;
                if (iA < gs) {                       // wave-uniform
                    l0 += eA0; l1 += eA1; l2 += eA2; l3 += eA3;
                    ac0.x += eA0*xA.x; ac0.y += eA0*xA.y; ac0.z += eA0*xA.z; ac0.w += eA0*xA.w;
                    ac1.x += eA1*xA.x; ac1.y += eA1*xA.y; ac1.z += eA1*xA.z; ac1.w += eA1*xA.w;
                    ac2.x += eA2*xA.x; ac2.y += eA2*xA.y; ac2.z += eA2*xA.z; ac2.w += eA2*xA.w;
                    ac3.x += eA3*xA.x; ac3.y += eA3*xA.y; ac3.z += eA3*xA.z; ac3.w += eA3*xA.w;
                    if (iA == lane) em = make_float4(eA0, eA1, eA2, eA3);
                }
                if (iB < gs) {                       // wave-uniform
                    l0 += eB0; l1 += eB1; l2 += eB2; l3 += eB3;
                    ac0.x += eB0*xB.x; ac0.y += eB0*xB.y; ac0.z += eB0*xB.z; ac0.w += eB0*xB.w;
                    ac1.x += eB1*xB.x; ac1.y += eB1*xB.y; ac1.z += eB1*xB.z; ac1.w += eB1*xB.w;
                    ac2.x += eB2*xB.x; ac2.y += eB2*xB.y; ac2.z += eB2*xB.z; ac2.w += eB2*xB.w;
                    ac3.x += eB3*xB.x; ac3.y += eB3*xB.y; ac3.z += eB3*xB.z; ac3.w += eB3*xB.w;
                    if (iB == lane) em = make_float4(eB0, eB1, eB2, eB3);
                }
            }
        }
        if (ngrp > 1 && lane < gs)                   // rare: spill e per 64-group
            ((float4*)ews)[s + g0 + lane] = em;
    }

    const float il0 = 1.f/l0, il1 = 1.f/l1, il2 = 1.f/l2, il3 = 1.f/l3;
    float4 out;
    out.x = 0.25f*(ac0.x*il0 + ac1.x*il1 + ac2.x*il2 + ac3.x*il3);
    out.y = 0.25f*(ac0.y*il0 + ac1.y*il1 + ac2.y*il2 + ac3.y*il3);
    out.z = 0.25f*(ac0.z*il0 + ac1.z*il1 + ac2.z*il2 + ac3.z*il3);
    out.w = 0.25f*(ac0.w*il0 + ac1.w*il1 + ac2.w*il2 + ac3.w*il3);
    ((float4*)xp)[(size_t)g * 64 + lane] = out;

    // attention weights [H, N]
    if (ngrp == 1) {
        if (lane < cnt) {                            // straight from registers
            aw[0 * (size_t)N + s + lane] = em.x * il0;
            aw[1 * (size_t)N + s + lane] = em.y * il1;
            aw[2 * (size_t)N + s + lane] = em.z * il2;
            aw[3 * (size_t)N + s + lane] = em.w * il3;
        }
    } else {
        asm volatile("s_waitcnt vmcnt(0)" ::: "memory");   // our ews stores visible
        for (int r = lane; r < cnt; r += 64) {
            const float4 ev = ((const float4*)ews)[s + r];
            aw[0 * (size_t)N + s + r] = ev.x * il0;
            aw[1 * (size_t)N + s + r] = ev.y * il1;
            aw[2 * (size_t)N + s + r] = ev.z * il2;
            aw[3 * (size_t)N + s + r] = ev.w * il3;
        }
    }
}

extern "C" void kernel_launch(void* const* d_in, const int* in_sizes, int n_in,
                              void* d_out, int out_size, void* d_ws, size_t ws_size,
                              hipStream_t stream) {
    const float* x    = (const float*)d_in[0];
    const int*   bi   = (const int*)d_in[1];
    // d_in[2] = num_graphs (derived from out_size)
    const float* W    = (const float*)d_in[3];
    const float* b    = (const float*)d_in[4];
    const float* temp = (const float*)d_in[5];

    const int N = in_sizes[0] / DD;
    const int G = (out_size - HH * N) / DD;

    float* xp = (float*)d_out;                    // [G, D]
    float* aw = (float*)d_out + (size_t)G * DD;   // [H, N]

    float* ews = (float*)d_ws;                    // N*H floats (rare spill)

    fused_single<<<(G * 64 + 255) / 256, 256, 0, stream>>>(
        x, bi, W, b, temp, ews, xp, aw, N, G);
}

// Round 18
// 64.748 us; speedup vs baseline: 1.0424x; 1.0424x over previous
//
#include <hip/hip_runtime.h>

#define DD 256
#define HH 4

// starts[g] = lower_bound(bi, g); starts[G] = N   (bi is sorted)
__global__ void starts_kernel(const int* __restrict__ bi, int* __restrict__ starts,
                              int N, int G) {
    int g = blockIdx.x * blockDim.x + threadIdx.x;
    if (g > G) return;
    int lo = 0, hi = N;
    while (lo < hi) { int mid = (lo + hi) >> 1; if (bi[mid] < g) lo = mid + 1; else hi = mid; }
    starts[g] = lo;
}

template <int CTRL>
__device__ __forceinline__ float dpp_add(float v) {
    const int t = __builtin_amdgcn_update_dpp(0, __float_as_int(v), CTRL, 0xF, 0xF, true);
    return v + __int_as_float(t);
}

// sum-to-all WITHIN each 32-lane half: 4 DPP levels + 1 shfl (xor16 stays in-half)
__device__ __forceinline__ float half_allsum(float v) {
    v = dpp_add<0xB1>(v);     // quad_perm [1,0,3,2]  (xor 1)
    v = dpp_add<0x4E>(v);     // quad_perm [2,3,0,1]  (xor 2)
    v = dpp_add<0x124>(v);    // row_ror:4
    v = dpp_add<0x128>(v);    // row_ror:8  -> row-of-16 sum
    v += __shfl_xor(v, 16);   // -> 32-lane-half sum
    return v;
}

// ONE WAVE per graph (r16 engine, verbatim) + __launch_bounds__(256,6):
// pin allocator to <=85 VGPR -> 6 waves/SIMD (r13/r16 proved this kernel is
// occupancy-sensitive; r16 estimated at ~90 VGPR = 5 waves/SIMD).
// Single coalesced x pass, zero LDS/barriers, split-row pair reduction
// (3 DS + 4 DPP + 1 exp per 2 rows per head), no-max softmax (validated r7-r17).
__global__ __launch_bounds__(256, 6) void fused_pair6(
    const float* __restrict__ x, const int* __restrict__ starts,
    const float* __restrict__ W, const float* __restrict__ b,
    const float* __restrict__ temp, float* __restrict__ ews,
    float* __restrict__ xp, float* __restrict__ aw, int N, int G) {

    const int lane = threadIdx.x & 63;
    const int half = lane >> 5;
    const int g = (int)((blockIdx.x * (size_t)blockDim.x + threadIdx.x) >> 6);
    if (g >= G) return;

    const int s = starts[g];
    const int e = starts[g + 1];
    const int cnt = e - s;

    if (cnt == 0) {
        ((float4*)xp)[(size_t)g * 64 + lane] = make_float4(0.f, 0.f, 0.f, 0.f);
        return;
    }

    const float4* __restrict__ x4 = (const float4*)x;
    const float4* __restrict__ W4 = (const float4*)W;
    const float4 w0 = W4[lane];            // lane's 4 columns of each head's W
    const float4 w1 = W4[64 + lane];
    const float4 w2 = W4[128 + lane];
    const float4 w3 = W4[192 + lane];
    const float invT = 1.0f / temp[0];
    const float b0 = b[0], b1 = b[1], b2 = b[2], b3 = b[3];

    const int ngrp = (cnt + 63) >> 6;      // almost always 1 (mean cnt ~31)

    float l0 = 0.f, l1 = 0.f, l2 = 0.f, l3 = 0.f;               // wave-uniform denom
    float4 ac0 = make_float4(0.f,0.f,0.f,0.f), ac1 = ac0, ac2 = ac0, ac3 = ac0;
    float4 em = make_float4(0.f, 0.f, 0.f, 0.f);                // my row's e (per group)

    for (int g0 = 0; g0 < cnt; g0 += 64) {
        const int gs = min(64, cnt - g0);
        for (int i = 0; i < gs; i += 4) {
            float4 xv[4];
            #pragma unroll
            for (int j = 0; j < 4; ++j) {
                const int r = s + g0 + i + j;
                xv[j] = x4[(size_t)(r < e ? r : e - 1) * 64 + lane];   // coalesced clause
            }
            #pragma unroll
            for (int pp = 0; pp < 2; ++pp) {
                const float4 xA = xv[2 * pp];
                const float4 xB = xv[2 * pp + 1];
                // per-lane 4-col partials for both rows, all heads
                const float pA0 = xA.x*w0.x + xA.y*w0.y + xA.z*w0.z + xA.w*w0.w;
                const float pA1 = xA.x*w1.x + xA.y*w1.y + xA.z*w1.z + xA.w*w1.w;
                const float pA2 = xA.x*w2.x + xA.y*w2.y + xA.z*w2.z + xA.w*w2.w;
                const float pA3 = xA.x*w3.x + xA.y*w3.y + xA.z*w3.z + xA.w*w3.w;
                const float pB0 = xB.x*w0.x + xB.y*w0.y + xB.z*w0.z + xB.w*w0.w;
                const float pB1 = xB.x*w1.x + xB.y*w1.y + xB.z*w1.z + xB.w*w1.w;
                const float pB2 = xB.x*w2.x + xB.y*w2.y + xB.z*w2.z + xB.w*w2.w;
                const float pB3 = xB.x*w3.x + xB.y*w3.y + xB.z*w3.z + xB.w*w3.w;
                // cross-half merge: half 0 keeps row A (sends B), half 1 keeps row B
                const float v0 = (half ? pB0 : pA0) + __shfl_xor(half ? pA0 : pB0, 32);
                const float v1 = (half ? pB1 : pA1) + __shfl_xor(half ? pA1 : pB1, 32);
                const float v2 = (half ? pB2 : pA2) + __shfl_xor(half ? pA2 : pB2, 32);
                const float v3 = (half ? pB3 : pA3) + __shfl_xor(half ? pA3 : pB3, 32);
                // reduce own row within the half; exp own row only
                const float eo0 = __expf((half_allsum(v0) + b0) * invT);
                const float eo1 = __expf((half_allsum(v1) + b1) * invT);
                const float eo2 = __expf((half_allsum(v2) + b2) * invT);
                const float eo3 = __expf((half_allsum(v3) + b3) * invT);
                // exchange finished e across halves
                const float eu0 = __shfl_xor(eo0, 32);
                const float eu1 = __shfl_xor(eo1, 32);
                const float eu2 = __shfl_xor(eo2, 32);
                const float eu3 = __shfl_xor(eo3, 32);
                const float eA0 = half ? eu0 : eo0, eB0 = half ? eo0 : eu0;
                const float eA1 = half ? eu1 : eo1, eB1 = half ? eo1 : eu1;
                const float eA2 = half ? eu2 : eo2, eB2 = half ? eo2 : eu2;
                const float eA3 = half ? eu3 : eo3, eB3 = half ? eo3 : eu3;

                const int iA = i + 2 * pp, iB = iA + 1;
                if (iA < gs) {                       // wave-uniform
                    l0 += eA0; l1 += eA1; l2 += eA2; l3 += eA3;
                    ac0.x += eA0*xA.x; ac0.y += eA0*xA.y; ac0.z += eA0*xA.z; ac0.w += eA0*xA.w;
                    ac1.x += eA1*xA.x; ac1.y += eA1*xA.y; ac1.z += eA1*xA.z; ac1.w += eA1*xA.w;
                    ac2.x += eA2*xA.x; ac2.y += eA2*xA.y; ac2.z += eA2*xA.z; ac2.w += eA2*xA.w;
                    ac3.x += eA3*xA.x; ac3.y += eA3*xA.y; ac3.z += eA3*xA.z; ac3.w += eA3*xA.w;
                    if (iA == lane) em = make_float4(eA0, eA1, eA2, eA3);
                }
                if (iB < gs) {                       // wave-uniform
                    l0 += eB0; l1 += eB1; l2 += eB2; l3 += eB3;
                    ac0.x += eB0*xB.x; ac0.y += eB0*xB.y; ac0.z += eB0*xB.z; ac0.w += eB0*xB.w;
                    ac1.x += eB1*xB.x; ac1.y += eB1*xB.y; ac1.z += eB1*xB.z; ac1.w += eB1*xB.w;
                    ac2.x += eB2*xB.x; ac2.y += eB2*xB.y; ac2.z += eB2*xB.z; ac2.w += eB2*xB.w;
                    ac3.x += eB3*xB.x; ac3.y += eB3*xB.y; ac3.z += eB3*xB.z; ac3.w += eB3*xB.w;
                    if (iB == lane) em = make_float4(eB0, eB1, eB2, eB3);
                }
            }
        }
        if (ngrp > 1 && lane < gs)                   // rare: spill e per 64-group
            ((float4*)ews)[s + g0 + lane] = em;
    }

    const float il0 = 1.f/l0, il1 = 1.f/l1, il2 = 1.f/l2, il3 = 1.f/l3;
    float4 out;
    out.x = 0.25f*(ac0.x*il0 + ac1.x*il1 + ac2.x*il2 + ac3.x*il3);
    out.y = 0.25f*(ac0.y*il0 + ac1.y*il1 + ac2.y*il2 + ac3.y*il3);
    out.z = 0.25f*(ac0.z*il0 + ac1.z*il1 + ac2.z*il2 + ac3.z*il3);
    out.w = 0.25f*(ac0.w*il0 + ac1.w*il1 + ac2.w*il2 + ac3.w*il3);
    ((float4*)xp)[(size_t)g * 64 + lane] = out;

    // attention weights [H, N]
    if (ngrp == 1) {
        if (lane < cnt) {                            // straight from registers
            aw[0 * (size_t)N + s + lane] = em.x * il0;
            aw[1 * (size_t)N + s + lane] = em.y * il1;
            aw[2 * (size_t)N + s + lane] = em.z * il2;
            aw[3 * (size_t)N + s + lane] = em.w * il3;
        }
    } else {
        asm volatile("s_waitcnt vmcnt(0)" ::: "memory");   // our ews stores visible
        for (int r = lane; r < cnt; r += 64) {
            const float4 ev = ((const float4*)ews)[s + r];
            aw[0 * (size_t)N + s + r] = ev.x * il0;
            aw[1 * (size_t)N + s + r] = ev.y * il1;
            aw[2 * (size_t)N + s + r] = ev.z * il2;
            aw[3 * (size_t)N + s + r] = ev.w * il3;
        }
    }
}

extern "C" void kernel_launch(void* const* d_in, const int* in_sizes, int n_in,
                              void* d_out, int out_size, void* d_ws, size_t ws_size,
                              hipStream_t stream) {
    const float* x    = (const float*)d_in[0];
    const int*   bi   = (const int*)d_in[1];
    // d_in[2] = num_graphs (derived from out_size)
    const float* W    = (const float*)d_in[3];
    const float* b    = (const float*)d_in[4];
    const float* temp = (const float*)d_in[5];

    const int N = in_sizes[0] / DD;
    const int G = (out_size - HH * N) / DD;

    float* xp = (float*)d_out;                    // [G, D]
    float* aw = (float*)d_out + (size_t)G * DD;   // [H, N]

    float* ews    = (float*)d_ws;                                  // N*H floats (rare spill)
    int*   starts = (int*)((char*)d_ws + (size_t)N * HH * 4);      // G+1 ints

    starts_kernel<<<(G + 1 + 255) / 256, 256, 0, stream>>>(bi, starts, N, G);
    fused_pair6<<<(G * 64 + 255) / 256, 256, 0, stream>>>(
        x, starts, W, b, temp, ews, xp, aw, N, G);
}

// Round 19
// 59.279 us; speedup vs baseline: 1.1385x; 1.0922x over previous
//
#include <hip/hip_runtime.h>

#define DD 256
#define HH 4

// starts[g] = lower_bound(bi, g); starts[G] = N   (bi is sorted)
__global__ void starts_kernel(const int* __restrict__ bi, int* __restrict__ starts,
                              int N, int G) {
    int g = blockIdx.x * blockDim.x + threadIdx.x;
    if (g > G) return;
    int lo = 0, hi = N;
    while (lo < hi) { int mid = (lo + hi) >> 1; if (bi[mid] < g) lo = mid + 1; else hi = mid; }
    starts[g] = lo;
}

template <int CTRL>
__device__ __forceinline__ float dpp_add(float v) {
    const int t = __builtin_amdgcn_update_dpp(0, __float_as_int(v), CTRL, 0xF, 0xF, true);
    return v + __int_as_float(t);
}

// sum-to-all WITHIN each 32-lane half: 4 DPP levels + 1 shfl (xor16 stays in-half)
__device__ __forceinline__ float half_allsum(float v) {
    v = dpp_add<0xB1>(v);     // quad_perm [1,0,3,2]  (xor 1)
    v = dpp_add<0x4E>(v);     // quad_perm [2,3,0,1]  (xor 2)
    v = dpp_add<0x124>(v);    // row_ror:4
    v = dpp_add<0x128>(v);    // row_ror:8  -> row-of-16 sum
    v += __shfl_xor(v, 16);   // -> 32-lane-half sum
    return v;
}

// ONE WAVE per graph (r16, the session optimum — 60.4 us).
// Single coalesced x pass (lane = column), ZERO LDS, ZERO barriers.
// Split-row pair reduction: rows processed in PAIRS; half 0 reduces row A,
// half 1 reduces row B. One pre-shfl merges cross-half partials for both rows,
// 5-level in-half reduce, exp of own row only, one post-shfl exchanges e.
// Per 2 rows per head: 3 DS + 4 DPP + 1 exp. No-max softmax (validated r7-r18).
// NOTE: no __launch_bounds__ min-wave pin — r18 proved pinning 6 waves/SIMD
// regresses (allocator squeeze); natural ~90 VGPR / 5 waves is optimal.
__global__ __launch_bounds__(256) void fused_pair(
    const float* __restrict__ x, const int* __restrict__ starts,
    const float* __restrict__ W, const float* __restrict__ b,
    const float* __restrict__ temp, float* __restrict__ ews,
    float* __restrict__ xp, float* __restrict__ aw, int N, int G) {

    const int lane = threadIdx.x & 63;
    const int half = lane >> 5;
    const int g = (int)((blockIdx.x * (size_t)blockDim.x + threadIdx.x) >> 6);
    if (g >= G) return;

    const int s = starts[g];
    const int e = starts[g + 1];
    const int cnt = e - s;

    if (cnt == 0) {
        ((float4*)xp)[(size_t)g * 64 + lane] = make_float4(0.f, 0.f, 0.f, 0.f);
        return;
    }

    const float4* __restrict__ x4 = (const float4*)x;
    const float4* __restrict__ W4 = (const float4*)W;
    const float4 w0 = W4[lane];            // lane's 4 columns of each head's W
    const float4 w1 = W4[64 + lane];
    const float4 w2 = W4[128 + lane];
    const float4 w3 = W4[192 + lane];
    const float invT = 1.0f / temp[0];
    const float b0 = b[0], b1 = b[1], b2 = b[2], b3 = b[3];

    const int ngrp = (cnt + 63) >> 6;      // almost always 1 (mean cnt ~31)

    float l0 = 0.f, l1 = 0.f, l2 = 0.f, l3 = 0.f;               // wave-uniform denom
    float4 ac0 = make_float4(0.f,0.f,0.f,0.f), ac1 = ac0, ac2 = ac0, ac3 = ac0;
    float4 em = make_float4(0.f, 0.f, 0.f, 0.f);                // my row's e (per group)

    for (int g0 = 0; g0 < cnt; g0 += 64) {
        const int gs = min(64, cnt - g0);
        for (int i = 0; i < gs; i += 4) {
            float4 xv[4];
            #pragma unroll
            for (int j = 0; j < 4; ++j) {
                const int r = s + g0 + i + j;
                xv[j] = x4[(size_t)(r < e ? r : e - 1) * 64 + lane];   // coalesced clause
            }
            #pragma unroll
            for (int pp = 0; pp < 2; ++pp) {
                const float4 xA = xv[2 * pp];
                const float4 xB = xv[2 * pp + 1];
                // per-lane 4-col partials for both rows, all heads
                const float pA0 = xA.x*w0.x + xA.y*w0.y + xA.z*w0.z + xA.w*w0.w;
                const float pA1 = xA.x*w1.x + xA.y*w1.y + xA.z*w1.z + xA.w*w1.w;
                const float pA2 = xA.x*w2.x + xA.y*w2.y + xA.z*w2.z + xA.w*w2.w;
                const float pA3 = xA.x*w3.x + xA.y*w3.y + xA.z*w3.z + xA.w*w3.w;
                const float pB0 = xB.x*w0.x + xB.y*w0.y + xB.z*w0.z + xB.w*w0.w;
                const float pB1 = xB.x*w1.x + xB.y*w1.y + xB.z*w1.z + xB.w*w1.w;
                const float pB2 = xB.x*w2.x + xB.y*w2.y + xB.z*w2.z + xB.w*w2.w;
                const float pB3 = xB.x*w3.x + xB.y*w3.y + xB.z*w3.z + xB.w*w3.w;
                // cross-half merge: half 0 keeps row A (sends B), half 1 keeps row B
                const float v0 = (half ? pB0 : pA0) + __shfl_xor(half ? pA0 : pB0, 32);
                const float v1 = (half ? pB1 : pA1) + __shfl_xor(half ? pA1 : pB1, 32);
                const float v2 = (half ? pB2 : pA2) + __shfl_xor(half ? pA2 : pB2, 32);
                const float v3 = (half ? pB3 : pA3) + __shfl_xor(half ? pA3 : pB3, 32);
                // reduce own row within the half; exp own row only
                const float eo0 = __expf((half_allsum(v0) + b0) * invT);
                const float eo1 = __expf((half_allsum(v1) + b1) * invT);
                const float eo2 = __expf((half_allsum(v2) + b2) * invT);
                const float eo3 = __expf((half_allsum(v3) + b3) * invT);
                // exchange finished e across halves
                const float eu0 = __shfl_xor(eo0, 32);
                const float eu1 = __shfl_xor(eo1, 32);
                const float eu2 = __shfl_xor(eo2, 32);
                const float eu3 = __shfl_xor(eo3, 32);
                const float eA0 = half ? eu0 : eo0, eB0 = half ? eo0 : eu0;
                const float eA1 = half ? eu1 : eo1, eB1 = half ? eo1 : eu1;
                const float eA2 = half ? eu2 : eo2, eB2 = half ? eo2 : eu2;
                const float eA3 = half ? eu3 : eo3, eB3 = half ? eo3 : eu3;

                const int iA = i + 2 * pp, iB = iA + 1;
                if (iA < gs) {                       // wave-uniform
                    l0 += eA0; l1 += eA1; l2 += eA2; l3 += eA3;
                    ac0.x += eA0*xA.x; ac0.y += eA0*xA.y; ac0.z += eA0*xA.z; ac0.w += eA0*xA.w;
                    ac1.x += eA1*xA.x; ac1.y += eA1*xA.y; ac1.z += eA1*xA.z; ac1.w += eA1*xA.w;
                    ac2.x += eA2*xA.x; ac2.y += eA2*xA.y; ac2.z += eA2*xA.z; ac2.w += eA2*xA.w;
                    ac3.x += eA3*xA.x; ac3.y += eA3*xA.y; ac3.z += eA3*xA.z; ac3.w += eA3*xA.w;
                    if (iA == lane) em = make_float4(eA0, eA1, eA2, eA3);
                }
                if (iB < gs) {                       // wave-uniform
                    l0 += eB0; l1 += eB1; l2 += eB2; l3 += eB3;
                    ac0.x += eB0*xB.x; ac0.y += eB0*xB.y; ac0.z += eB0*xB.z; ac0.w += eB0*xB.w;
                    ac1.x += eB1*xB.x; ac1.y += eB1*xB.y; ac1.z += eB1*xB.z; ac1.w += eB1*xB.w;
                    ac2.x += eB2*xB.x; ac2.y += eB2*xB.y; ac2.z += eB2*xB.z; ac2.w += eB2*xB.w;
                    ac3.x += eB3*xB.x; ac3.y += eB3*xB.y; ac3.z += eB3*xB.z; ac3.w += eB3*xB.w;
                    if (iB == lane) em = make_float4(eB0, eB1, eB2, eB3);
                }
            }
        }
        if (ngrp > 1 && lane < gs)                   // rare: spill e per 64-group
            ((float4*)ews)[s + g0 + lane] = em;
    }

    const float il0 = 1.f/l0, il1 = 1.f/l1, il2 = 1.f/l2, il3 = 1.f/l3;
    float4 out;
    out.x = 0.25f*(ac0.x*il0 + ac1.x*il1 + ac2.x*il2 + ac3.x*il3);
    out.y = 0.25f*(ac0.y*il0 + ac1.y*il1 + ac2.y*il2 + ac3.y*il3);
    out.z = 0.25f*(ac0.z*il0 + ac1.z*il1 + ac2.z*il2 + ac3.z*il3);
    out.w = 0.25f*(ac0.w*il0 + ac1.w*il1 + ac2.w*il2 + ac3.w*il3);
    ((float4*)xp)[(size_t)g * 64 + lane] = out;

    // attention weights [H, N]
    if (ngrp == 1) {
        if (lane < cnt) {                            // straight from registers
            aw[0 * (size_t)N + s + lane] = em.x * il0;
            aw[1 * (size_t)N + s + lane] = em.y * il1;
            aw[2 * (size_t)N + s + lane] = em.z * il2;
            aw[3 * (size_t)N + s + lane] = em.w * il3;
        }
    } else {
        asm volatile("s_waitcnt vmcnt(0)" ::: "memory");   // our ews stores visible
        for (int r = lane; r < cnt; r += 64) {
            const float4 ev = ((const float4*)ews)[s + r];
            aw[0 * (size_t)N + s + r] = ev.x * il0;
            aw[1 * (size_t)N + s + r] = ev.y * il1;
            aw[2 * (size_t)N + s + r] = ev.z * il2;
            aw[3 * (size_t)N + s + r] = ev.w * il3;
        }
    }
}

extern "C" void kernel_launch(void* const* d_in, const int* in_sizes, int n_in,
                              void* d_out, int out_size, void* d_ws, size_t ws_size,
                              hipStream_t stream) {
    const float* x    = (const float*)d_in[0];
    const int*   bi   = (const int*)d_in[1];
    // d_in[2] = num_graphs (derived from out_size)
    const float* W    = (const float*)d_in[3];
    const float* b    = (const float*)d_in[4];
    const float* temp = (const float*)d_in[5];

    const int N = in_sizes[0] / DD;
    const int G = (out_size - HH * N) / DD;

    float* xp = (float*)d_out;                    // [G, D]
    float* aw = (float*)d_out + (size_t)G * DD;   // [H, N]

    float* ews    = (float*)d_ws;                                  // N*H floats (rare spill)
    int*   starts = (int*)((char*)d_ws + (size_t)N * HH * 4);      // G+1 ints

    starts_kernel<<<(G + 1 + 255) / 256, 256, 0, stream>>>(bi, starts, N, G);
    fused_pair<<<(G * 64 + 255) / 256, 256, 0, stream>>>(
        x, starts, W, b, temp, ews, xp, aw, N, G);
}